// Round 6
// baseline (487.448 us; speedup 1.0000x reference)
//
#include <hip/hip_runtime.h>
#include <hip/hip_fp16.h>

// GraphSAGE 2-layer: N=50000, D=128, DEG=16. f16 pipeline.
// R6: XCD-affine gather via HW_REG_XCC_ID + per-slice atomic work queues
//     (mapping-independent). Feature tables column-sliced 4 x 3.2MB so each
//     XCD's random gather reads stay inside its private 4MB L2.
typedef _Float16 half8v __attribute__((ext_vector_type(8)));
typedef __attribute__((ext_vector_type(4))) float f32x4;

#define N_NODES 50000
#define D 128
#define DEG 16
#define K2 256     // 2*D
#define BM 64      // rows per chunk / GEMM block
#define NCH 782    // ceil(50000/64) chunks per slice
#define SLS (N_NODES * 32)   // slice stride in elements (3.2 MB)

static __device__ __forceinline__ unsigned short f2h(float f) {
    return __half_as_ushort(__float2half(f));
}

// ---- prep: x -> f16 sliced ; W -> f16 transposed ; zero the 8 work counters ----
__global__ void prep(const float* __restrict__ x, unsigned short* __restrict__ xh,
                     const float* __restrict__ W1, const float* __restrict__ W2,
                     unsigned short* __restrict__ Wt1, unsigned short* __restrict__ Wt2,
                     int* __restrict__ ctr) {
    int b = blockIdx.x;
    int tid = threadIdx.x;
    if (b == 0 && tid < 8) ctr[tid] = 0;
    if (b < 128) {
        int i = b * 256 + tid;               // [0, K2*D)
        int k = i / D, n = i % D;
        Wt1[n * K2 + k] = f2h(W1[i]);
        Wt2[n * K2 + k] = f2h(W2[i]);
    } else {
        int row = (b - 128) * 16 + (tid >> 4);   // 16 rows/block
        int p   = tid & 15;                       // 8-dim part
        const float* sp = x + (size_t)row * D + p * 8;
        float4 v0 = *(const float4*)(sp);
        float4 v1 = *(const float4*)(sp + 4);
        ushort4 o0, o1;
        o0.x = f2h(v0.x); o0.y = f2h(v0.y); o0.z = f2h(v0.z); o0.w = f2h(v0.w);
        o1.x = f2h(v1.x); o1.y = f2h(v1.y); o1.z = f2h(v1.z); o1.w = f2h(v1.w);
        int s = p >> 2;                           // slice 0..3
        unsigned short* dp = xh + (size_t)s * SLS + (size_t)row * 32 + (p & 3) * 8;
        *(ushort4*)(dp)     = o0;
        *(ushort4*)(dp + 4) = o1;
    }
}

// ---- gather: per-slice work queues, XCD-affine via HW_REG_XCC_ID ----
__global__ __launch_bounds__(256, 4)
void gather_mean(const unsigned short* __restrict__ tb,   // sliced feats
                 const int* __restrict__ nbr,
                 unsigned short* __restrict__ meanbuf,    // N x D f16 row-major
                 int* __restrict__ ctr)                   // 4 counters
{
    __shared__ int Nl[BM * DEG];
    __shared__ int s_task;
    const int tid = threadIdx.x;

    unsigned xcc;
    asm volatile("s_getreg_b32 %0, hwreg(HW_REG_XCC_ID)" : "=s"(xcc));
    const int pref = (int)(xcc & 3u);

    const int r = tid >> 2;          // row within chunk 0..63
    const int q = tid & 3;           // 16B quarter of the 64B slice-row

    for (int a = 0; a < 4; ++a) {
        const int s = (pref + a) & 3;
        const unsigned short* t = tb + (size_t)s * SLS + q * 8;
        while (true) {
            __syncthreads();                       // protect s_task / Nl reuse
            if (tid == 0) s_task = atomicAdd(ctr + s, 1);
            __syncthreads();
            const int ck = s_task;
            if (ck >= NCH) break;
            const int row0 = ck * BM;

            int g = row0 * DEG + tid * 4;
            int gmax = N_NODES * DEG - 4;
            if (g > gmax) g = gmax;
            *(int4*)(Nl + tid * 4) = *(const int4*)(nbr + g);
            __syncthreads();

            int4 i0 = *(const int4*)(Nl + r * 16);
            int4 i1 = *(const int4*)(Nl + r * 16 + 4);
            int4 i2 = *(const int4*)(Nl + r * 16 + 8);
            int4 i3 = *(const int4*)(Nl + r * 16 + 12);
            int ids[16] = { i0.x, i0.y, i0.z, i0.w, i1.x, i1.y, i1.z, i1.w,
                            i2.x, i2.y, i2.z, i2.w, i3.x, i3.y, i3.z, i3.w };

            uint4 v[16];
            #pragma unroll
            for (int j = 0; j < 16; ++j)
                v[j] = *(const uint4*)(t + (size_t)ids[j] * 32);

            __half2 am[4];
            #pragma unroll
            for (int i = 0; i < 4; ++i) am[i] = __half2(__float2half(0.f), __float2half(0.f));
            #pragma unroll
            for (int j = 0; j < 16; ++j) {
                union { uint4 u; __half2 h[4]; } cv; cv.u = v[j];
                #pragma unroll
                for (int i = 0; i < 4; ++i) am[i] = __hadd2(am[i], cv.h[i]);
            }
            const __half2 sc = __half2(__float2half(0.0625f), __float2half(0.0625f));
            union { uint4 u; __half2 h[4]; } mv;
            #pragma unroll
            for (int i = 0; i < 4; ++i) mv.h[i] = __hmul2(am[i], sc);

            const int row = row0 + r;
            if (row < N_NODES)
                *(uint4*)(meanbuf + (size_t)row * D + s * 32 + q * 8) = mv.u;
        }
    }
}

// ---- GEMM: out = relu([self | mean] @ W + b) ----
template <int OUT_SLICED_F16>
__global__ __launch_bounds__(256)
void gemm_sage(const unsigned short* __restrict__ tb,       // sliced self feats
               const unsigned short* __restrict__ meanbuf,  // N x D f16
               const unsigned short* __restrict__ wt,       // D x K2 f16 (n-major)
               const float* __restrict__ bias,
               void* __restrict__ out)
{
    __shared__ __align__(16) unsigned short Hl[BM * 264];
    const int tid  = threadIdx.x;
    const int row0 = blockIdx.x * BM;

    #pragma unroll
    for (int i = 0; i < 8; ++i) {
        int c   = tid + i * 256;
        int r   = c >> 5;
        int off = (c & 31) * 8;       // dim offset 0..248
        int row = row0 + r;
        if (row >= N_NODES) row = N_NODES - 1;
        uint4 d;
        if (off < D) {
            int s = off >> 5;
            d = *(const uint4*)(tb + (size_t)s * SLS + (size_t)row * 32 + (off & 31));
        } else {
            d = *(const uint4*)(meanbuf + (size_t)row * D + (off - D));
        }
        *(uint4*)(&Hl[r * 264 + off]) = d;
    }

    const int lane = tid & 63;
    const int w    = tid >> 6;
    const int quad = lane >> 4;
    const int l16  = lane & 15;
    const int n_base = w * 32;
    half8v bfrag[8][2];
    #pragma unroll
    for (int kk = 0; kk < 8; ++kk)
        #pragma unroll
        for (int ct = 0; ct < 2; ++ct)
            bfrag[kk][ct] = *(const half8v*)(wt + (n_base + ct * 16 + l16) * K2 + kk * 32 + quad * 8);

    __syncthreads();

    f32x4 acc[4][2];
    #pragma unroll
    for (int rt = 0; rt < 4; ++rt)
        #pragma unroll
        for (int ct = 0; ct < 2; ++ct)
            acc[rt][ct] = (f32x4){0.f, 0.f, 0.f, 0.f};

    #pragma unroll
    for (int kk = 0; kk < 8; ++kk) {
        half8v afrag[4];
        #pragma unroll
        for (int rt = 0; rt < 4; ++rt)
            afrag[rt] = *(const half8v*)(&Hl[(rt * 16 + l16) * 264 + kk * 32 + quad * 8]);
        #pragma unroll
        for (int rt = 0; rt < 4; ++rt)
            #pragma unroll
            for (int ct = 0; ct < 2; ++ct)
                acc[rt][ct] = __builtin_amdgcn_mfma_f32_16x16x32_f16(
                    afrag[rt], bfrag[kk][ct], acc[rt][ct], 0, 0, 0);
    }

    float bv0 = bias[n_base + l16];
    float bv1 = bias[n_base + 16 + l16];
    #pragma unroll
    for (int rt = 0; rt < 4; ++rt) {
        int grow_base = row0 + rt * 16 + quad * 4;
        #pragma unroll
        for (int r = 0; r < 4; ++r) {
            int grow = grow_base + r;
            if (grow >= N_NODES) continue;
            #pragma unroll
            for (int ct = 0; ct < 2; ++ct) {
                float vv = acc[rt][ct][r] + (ct ? bv1 : bv0);
                vv = vv > 0.f ? vv : 0.f;
                int col = n_base + ct * 16 + l16;
                if (OUT_SLICED_F16) {
                    int s = col >> 5;
                    ((unsigned short*)out)[(size_t)s * SLS + (size_t)grow * 32 + (col & 31)] = f2h(vv);
                } else {
                    ((float*)out)[(size_t)grow * D + col] = vv;
                }
            }
        }
    }
}

extern "C" void kernel_launch(void* const* d_in, const int* in_sizes, int n_in,
                              void* d_out, int out_size, void* d_ws, size_t ws_size,
                              hipStream_t stream) {
    const float* x  = (const float*)d_in[0];
    const int*   nb = (const int*)d_in[1];
    const float* W1 = (const float*)d_in[2];
    const float* b1 = (const float*)d_in[3];
    const float* W2 = (const float*)d_in[4];
    const float* b2 = (const float*)d_in[5];

    char* ws = (char*)d_ws;
    int*            ctr  = (int*)ws;                                         // 8 counters
    unsigned short* Wt1  = (unsigned short*)(ws + 1024);
    unsigned short* Wt2  = (unsigned short*)(ws + 1024 + 65536);
    unsigned short* xh   = (unsigned short*)(ws + 1024 + 131072);            // 4 slices, 12.8MB
    unsigned short* h1   = (unsigned short*)(ws + 1024 + 131072 + 12800000); // 4 slices, 12.8MB
    unsigned short* mean = (unsigned short*)(ws + 1024 + 131072 + 2 * 12800000);

    prep<<<128 + 3125, 256, 0, stream>>>(x, xh, W1, W2, Wt1, Wt2, ctr);

    const int ggrid = 4 * NCH;                  // 3128 blocks = 3128 tasks
    const int mgrid = (N_NODES + BM - 1) / BM;  // 782

    gather_mean<<<ggrid, 256, 0, stream>>>(xh, nb, mean, ctr);
    gemm_sage<1><<<mgrid, 256, 0, stream>>>(xh, mean, Wt1, b1, h1);
    gather_mean<<<ggrid, 256, 0, stream>>>(h1, nb, mean, ctr + 4);
    gemm_sage<0><<<mgrid, 256, 0, stream>>>(h1, mean, Wt2, b2, d_out);
}

// Round 7
// 167.841 us; speedup vs baseline: 2.9042x; 2.9042x over previous
//
#include <hip/hip_runtime.h>
#include <hip/hip_fp16.h>

// GraphSAGE 2-layer: N=50000, D=128, DEG=16. f16 pipeline.
// R7: XCD-affine gather via HW_REG_XCC_ID + ONE atomic claim per block on
//     cacheline-padded per-XCD counters (R6's 185us pathology = 12.5k atomics
//     on a single cacheline; now 3.1k atomics on 8 separate lines).
//     Feature tables column-sliced 4 x 3.2MB (32 dims, 64B rows = 1 cacheline)
//     so each XCD's random gather reads stay inside its private 4MB L2.
typedef _Float16 half8v __attribute__((ext_vector_type(8)));
typedef __attribute__((ext_vector_type(4))) float f32x4;

#define N_NODES 50000
#define D 128
#define DEG 16
#define K2 256     // 2*D
#define BM 64      // rows per chunk / GEMM block
#define HALF_ROWS 25000
#define NCHH 391   // ceil(25000/64) chunks per xcc-group
#define SLS (N_NODES * 32)   // slice stride in elements (3.2 MB)
#define CPAD 64    // counter padding: 64 ints = 256B

static __device__ __forceinline__ unsigned short f2h(float f) {
    return __half_as_ushort(__float2half(f));
}

// ---- prep: x -> f16 sliced ; W -> f16 transposed ; zero the 16 padded counters ----
__global__ void prep(const float* __restrict__ x, unsigned short* __restrict__ xh,
                     const float* __restrict__ W1, const float* __restrict__ W2,
                     unsigned short* __restrict__ Wt1, unsigned short* __restrict__ Wt2,
                     int* __restrict__ ctr) {
    int b = blockIdx.x;
    int tid = threadIdx.x;
    if (b == 0 && tid < 16) ctr[tid * CPAD] = 0;
    if (b < 128) {
        int i = b * 256 + tid;               // [0, K2*D)
        int k = i / D, n = i % D;
        Wt1[n * K2 + k] = f2h(W1[i]);
        Wt2[n * K2 + k] = f2h(W2[i]);
    } else {
        int row = (b - 128) * 16 + (tid >> 4);   // 16 rows/block
        int p   = tid & 15;                       // 8-dim part
        const float* sp = x + (size_t)row * D + p * 8;
        float4 v0 = *(const float4*)(sp);
        float4 v1 = *(const float4*)(sp + 4);
        ushort4 o0, o1;
        o0.x = f2h(v0.x); o0.y = f2h(v0.y); o0.z = f2h(v0.z); o0.w = f2h(v0.w);
        o1.x = f2h(v1.x); o1.y = f2h(v1.y); o1.z = f2h(v1.z); o1.w = f2h(v1.w);
        int s = p >> 2;                           // slice 0..3
        unsigned short* dp = xh + (size_t)s * SLS + (size_t)row * 32 + (p & 3) * 8;
        *(ushort4*)(dp)     = o0;
        *(ushort4*)(dp + 4) = o1;
    }
}

// ---- gather: one task claim per block, XCD-affine, padded counters ----
__global__ __launch_bounds__(256, 4)
void gather_mean(const unsigned short* __restrict__ tb,   // sliced feats
                 const int* __restrict__ nbr,
                 unsigned short* __restrict__ meanbuf,    // N x D f16 row-major
                 int* __restrict__ ctr)                   // 8 padded counters
{
    __shared__ int Nl[BM * DEG];
    __shared__ int s_task;
    const int tid = threadIdx.x;

    if (tid == 0) {
        unsigned xcc;
        asm volatile("s_getreg_b32 %0, hwreg(HW_REG_XCC_ID)" : "=s"(xcc));
        int hg = (int)(xcc & 7u);
        int k = atomicAdd(ctr + hg * CPAD, 1);
        if (k >= NCHH) {
            k = -1;
            #pragma unroll 1
            for (int o = 1; o < 8; ++o) {
                int g2 = (hg + o) & 7;
                int k2 = atomicAdd(ctr + g2 * CPAD, 1);
                if (k2 < NCHH) { hg = g2; k = k2; break; }
            }
        }
        s_task = (k < 0) ? -1 : (hg * NCHH + k);
    }
    __syncthreads();
    const int task = s_task;
    if (task < 0) return;

    const int hg    = task / NCHH;
    const int ck    = task - hg * NCHH;
    const int slice = hg & 3;
    const int half  = hg >> 2;
    const int row0  = half * HALF_ROWS + ck * BM;
    const int rowEnd = half * HALF_ROWS + HALF_ROWS;

    {   // stage indices
        int g = row0 * DEG + tid * 4;
        int gmax = N_NODES * DEG - 4;
        if (g > gmax) g = gmax;
        *(int4*)(Nl + tid * 4) = *(const int4*)(nbr + g);
    }
    __syncthreads();

    const int r = tid >> 2;          // row within chunk 0..63
    const int q = tid & 3;           // 16B quarter of the 64B slice-row
    int row = row0 + r;
    bool valid = row < rowEnd;

    int4 i0 = *(const int4*)(Nl + r * 16);
    int4 i1 = *(const int4*)(Nl + r * 16 + 4);
    int4 i2 = *(const int4*)(Nl + r * 16 + 8);
    int4 i3 = *(const int4*)(Nl + r * 16 + 12);
    int ids[16] = { i0.x, i0.y, i0.z, i0.w, i1.x, i1.y, i1.z, i1.w,
                    i2.x, i2.y, i2.z, i2.w, i3.x, i3.y, i3.z, i3.w };

    const unsigned short* t = tb + (size_t)slice * SLS + q * 8;
    uint4 v[16];
    #pragma unroll
    for (int j = 0; j < 16; ++j)
        v[j] = *(const uint4*)(t + (size_t)ids[j] * 32);

    __half2 am[4];
    #pragma unroll
    for (int i = 0; i < 4; ++i) am[i] = __half2(__float2half(0.f), __float2half(0.f));
    #pragma unroll
    for (int j = 0; j < 16; ++j) {
        union { uint4 u; __half2 h[4]; } cv; cv.u = v[j];
        #pragma unroll
        for (int i = 0; i < 4; ++i) am[i] = __hadd2(am[i], cv.h[i]);
    }
    const __half2 sc = __half2(__float2half(0.0625f), __float2half(0.0625f));
    union { uint4 u; __half2 h[4]; } mv;
    #pragma unroll
    for (int i = 0; i < 4; ++i) mv.h[i] = __hmul2(am[i], sc);

    if (valid)
        *(uint4*)(meanbuf + (size_t)row * D + slice * 32 + q * 8) = mv.u;
}

// ---- GEMM: out = relu([self | mean] @ W + b) ----
template <int OUT_SLICED_F16>
__global__ __launch_bounds__(256)
void gemm_sage(const unsigned short* __restrict__ tb,       // sliced self feats
               const unsigned short* __restrict__ meanbuf,  // N x D f16
               const unsigned short* __restrict__ wt,       // D x K2 f16 (n-major)
               const float* __restrict__ bias,
               void* __restrict__ out)
{
    __shared__ __align__(16) unsigned short Hl[BM * 264];
    const int tid  = threadIdx.x;
    const int row0 = blockIdx.x * BM;

    #pragma unroll
    for (int i = 0; i < 8; ++i) {
        int c   = tid + i * 256;
        int r   = c >> 5;
        int off = (c & 31) * 8;       // dim offset 0..248
        int row = row0 + r;
        if (row >= N_NODES) row = N_NODES - 1;
        uint4 d;
        if (off < D) {
            int s = off >> 5;
            d = *(const uint4*)(tb + (size_t)s * SLS + (size_t)row * 32 + (off & 31));
        } else {
            d = *(const uint4*)(meanbuf + (size_t)row * D + (off - D));
        }
        *(uint4*)(&Hl[r * 264 + off]) = d;
    }

    const int lane = tid & 63;
    const int w    = tid >> 6;
    const int quad = lane >> 4;
    const int l16  = lane & 15;
    const int n_base = w * 32;
    half8v bfrag[8][2];
    #pragma unroll
    for (int kk = 0; kk < 8; ++kk)
        #pragma unroll
        for (int ct = 0; ct < 2; ++ct)
            bfrag[kk][ct] = *(const half8v*)(wt + (n_base + ct * 16 + l16) * K2 + kk * 32 + quad * 8);

    __syncthreads();

    f32x4 acc[4][2];
    #pragma unroll
    for (int rt = 0; rt < 4; ++rt)
        #pragma unroll
        for (int ct = 0; ct < 2; ++ct)
            acc[rt][ct] = (f32x4){0.f, 0.f, 0.f, 0.f};

    #pragma unroll
    for (int kk = 0; kk < 8; ++kk) {
        half8v afrag[4];
        #pragma unroll
        for (int rt = 0; rt < 4; ++rt)
            afrag[rt] = *(const half8v*)(&Hl[(rt * 16 + l16) * 264 + kk * 32 + quad * 8]);
        #pragma unroll
        for (int rt = 0; rt < 4; ++rt)
            #pragma unroll
            for (int ct = 0; ct < 2; ++ct)
                acc[rt][ct] = __builtin_amdgcn_mfma_f32_16x16x32_f16(
                    afrag[rt], bfrag[kk][ct], acc[rt][ct], 0, 0, 0);
    }

    float bv0 = bias[n_base + l16];
    float bv1 = bias[n_base + 16 + l16];
    #pragma unroll
    for (int rt = 0; rt < 4; ++rt) {
        int grow_base = row0 + rt * 16 + quad * 4;
        #pragma unroll
        for (int r = 0; r < 4; ++r) {
            int grow = grow_base + r;
            if (grow >= N_NODES) continue;
            #pragma unroll
            for (int ct = 0; ct < 2; ++ct) {
                float vv = acc[rt][ct][r] + (ct ? bv1 : bv0);
                vv = vv > 0.f ? vv : 0.f;
                int col = n_base + ct * 16 + l16;
                if (OUT_SLICED_F16) {
                    int s = col >> 5;
                    ((unsigned short*)out)[(size_t)s * SLS + (size_t)grow * 32 + (col & 31)] = f2h(vv);
                } else {
                    ((float*)out)[(size_t)grow * D + col] = vv;
                }
            }
        }
    }
}

extern "C" void kernel_launch(void* const* d_in, const int* in_sizes, int n_in,
                              void* d_out, int out_size, void* d_ws, size_t ws_size,
                              hipStream_t stream) {
    const float* x  = (const float*)d_in[0];
    const int*   nb = (const int*)d_in[1];
    const float* W1 = (const float*)d_in[2];
    const float* b1 = (const float*)d_in[3];
    const float* W2 = (const float*)d_in[4];
    const float* b2 = (const float*)d_in[5];

    char* ws = (char*)d_ws;
    int*            ctr  = (int*)ws;                                          // 16 padded counters (4KB)
    unsigned short* Wt1  = (unsigned short*)(ws + 8192);
    unsigned short* Wt2  = (unsigned short*)(ws + 8192 + 65536);
    unsigned short* xh   = (unsigned short*)(ws + 8192 + 131072);             // 4 slices, 12.8MB
    unsigned short* h1   = (unsigned short*)(ws + 8192 + 131072 + 12800000);  // 4 slices, 12.8MB
    unsigned short* mean = (unsigned short*)(ws + 8192 + 131072 + 2 * 12800000);

    prep<<<128 + 3125, 256, 0, stream>>>(x, xh, W1, W2, Wt1, Wt2, ctr);

    const int ggrid = 8 * NCHH;                 // 3128 blocks = 3128 tasks
    const int mgrid = (N_NODES + BM - 1) / BM;  // 782

    gather_mean<<<ggrid, 256, 0, stream>>>(xh, nb, mean, ctr);
    gemm_sage<1><<<mgrid, 256, 0, stream>>>(xh, mean, Wt1, b1, h1);
    gather_mean<<<ggrid, 256, 0, stream>>>(h1, nb, mean, ctr + 8 * CPAD);
    gemm_sage<0><<<mgrid, 256, 0, stream>>>(h1, mean, Wt2, b2, d_out);
}

// Round 8
// 158.589 us; speedup vs baseline: 3.0737x; 1.0583x over previous
//
#include <hip/hip_runtime.h>
#include <hip/hip_fp16.h>

// GraphSAGE 2-layer: N=50000, D=128, DEG=16. f16 pipeline, 3 launches.
// R8: fused gather+GEMM with concurrency fix:
//   - BM=32, 2 waves/block; each wave stages its own 16-row half (wave-private
//     neighbor ids + gather + mean) -> ONE barrier total (A-tile share).
//   - B-fragments streamed from L2 in the k-loop (wt 64KB L2-resident) instead
//     of 64 resident VGPRs -> VGPR <= ~100 -> ~9 blocks (18 waves)/CU vs R3's 12.
typedef _Float16 half8v __attribute__((ext_vector_type(8)));
typedef __attribute__((ext_vector_type(4))) float f32x4;

#define N_NODES 50000
#define D 128
#define DEG 16
#define K2 256     // 2*D
#define BM 32      // rows per block (16 per wave)
#define LDA 264    // A-tile row stride (elems), pad 8

static __device__ __forceinline__ unsigned short f2h(float f) {
    return __half_as_ushort(__float2half(f));
}

// ---- prep: x -> f16 row-major ; W1,W2 -> f16 transposed (n-major) ----
__global__ void prep(const float* __restrict__ x, unsigned short* __restrict__ xh,
                     const float* __restrict__ W1, const float* __restrict__ W2,
                     unsigned short* __restrict__ Wt1, unsigned short* __restrict__ Wt2) {
    int b = blockIdx.x;
    int tid = threadIdx.x;
    if (b < 128) {
        int i = b * 256 + tid;               // [0, K2*D)
        int k = i / D, n = i % D;
        Wt1[n * K2 + k] = f2h(W1[i]);
        Wt2[n * K2 + k] = f2h(W2[i]);
    } else {
        int i = ((b - 128) * 256 + tid) * 4;
        if (i < N_NODES * D) {
            float4 v = *(const float4*)(x + i);
            ushort4 o;
            o.x = f2h(v.x); o.y = f2h(v.y); o.z = f2h(v.z); o.w = f2h(v.w);
            *(ushort4*)(xh + i) = o;
        }
    }
}

// ---- fused layer: out = relu( [feat | mean_nbr(feat)] @ W + b ) ----
template <int OUT_F16>
__global__ __launch_bounds__(128, 4)
void sage_layer(const unsigned short* __restrict__ feat,  // N x D f16
                const int* __restrict__ nbr,              // N x DEG
                const unsigned short* __restrict__ wt,    // D x K2 f16 (n-major)
                const float* __restrict__ bias,           // D f32
                void* __restrict__ out)
{
    __shared__ __align__(16) unsigned short Hl[BM * LDA];  // 32 x 264 A tile
    __shared__ int Nl[BM * DEG];                           // 512 ids
    const int tid  = threadIdx.x;
    const int w    = tid >> 6;        // wave 0/1
    const int lane = tid & 63;
    const int row0 = blockIdx.x * BM;

    // stage neighbor ids: threads of wave w write exactly Nl[w*256 .. w*256+255]
    // (ids for rows w*16..w*16+15) -> wave-private, no barrier needed before use.
    {
        int g = row0 * DEG + tid * 4;
        int gmax = N_NODES * DEG - 4;
        if (g > gmax) g = gmax;
        *(int4*)(Nl + tid * 4) = *(const int4*)(nbr + g);
    }

    // ---- gather phase (wave-private 16 rows): 4 units of (row, 8-dim slice)
    const int s = lane & 15;                 // dim slice (16B)
    #pragma unroll
    for (int u = 0; u < 4; ++u) {
        const int r = w * 16 + (lane >> 4) + u * 4;   // 0..31 (block-local)
        int grow = row0 + r;
        if (grow >= N_NODES) grow = N_NODES - 1;
        uint4 self = *(const uint4*)(feat + (size_t)grow * D + s * 8);

        const int* idp = Nl + r * DEG;       // LDS; wave-private (lgkmcnt ordered)
        __half2 am[4];
        #pragma unroll
        for (int i = 0; i < 4; ++i) am[i] = __half2(__float2half(0.f), __float2half(0.f));

        #pragma unroll
        for (int b = 0; b < 2; ++b) {
            int4 ia = *(const int4*)(idp + b * 8);
            int4 ib = *(const int4*)(idp + b * 8 + 4);
            int ids[8] = { ia.x, ia.y, ia.z, ia.w, ib.x, ib.y, ib.z, ib.w };
            uint4 v[8];
            #pragma unroll
            for (int j = 0; j < 8; ++j)
                v[j] = *(const uint4*)(feat + (size_t)ids[j] * D + s * 8);
            #pragma unroll
            for (int j = 0; j < 8; ++j) {
                union { uint4 u4; __half2 h[4]; } cv; cv.u4 = v[j];
                #pragma unroll
                for (int i = 0; i < 4; ++i) am[i] = __hadd2(am[i], cv.h[i]);
            }
        }
        const __half2 sc = __half2(__float2half(0.0625f), __float2half(0.0625f));
        union { uint4 u4; __half2 h[4]; } mv;
        #pragma unroll
        for (int i = 0; i < 4; ++i) mv.h[i] = __hmul2(am[i], sc);

        unsigned short* hr = Hl + r * LDA + s * 8;
        *(uint4*)(hr)     = self;
        *(uint4*)(hr + D) = mv.u4;
    }

    __syncthreads();   // the ONE barrier: waves exchange A-tile halves

    // ---- MFMA: each wave computes 32 rows x 64 cols (its col-half)
    const int quad = lane >> 4;
    const int l16  = lane & 15;
    const int n_base = w * 64;

    f32x4 acc[2][4];
    #pragma unroll
    for (int rt = 0; rt < 2; ++rt)
        #pragma unroll
        for (int ct = 0; ct < 4; ++ct)
            acc[rt][ct] = (f32x4){0.f, 0.f, 0.f, 0.f};

    #pragma unroll
    for (int kk = 0; kk < 8; ++kk) {
        half8v a0 = *(const half8v*)(&Hl[l16 * LDA + kk * 32 + quad * 8]);
        half8v a1 = *(const half8v*)(&Hl[(16 + l16) * LDA + kk * 32 + quad * 8]);
        #pragma unroll
        for (int ct = 0; ct < 4; ++ct) {
            half8v bf = *(const half8v*)(wt + (size_t)(n_base + ct * 16 + l16) * K2 + kk * 32 + quad * 8);
            acc[0][ct] = __builtin_amdgcn_mfma_f32_16x16x32_f16(a0, bf, acc[0][ct], 0, 0, 0);
            acc[1][ct] = __builtin_amdgcn_mfma_f32_16x16x32_f16(a1, bf, acc[1][ct], 0, 0, 0);
        }
    }

    // ---- epilogue: C[row0 + rt*16 + quad*4 + i][n_base + ct*16 + l16]
    float bv[4];
    #pragma unroll
    for (int ct = 0; ct < 4; ++ct) bv[ct] = bias[n_base + ct * 16 + l16];

    #pragma unroll
    for (int rt = 0; rt < 2; ++rt) {
        int grow_base = row0 + rt * 16 + quad * 4;
        #pragma unroll
        for (int i = 0; i < 4; ++i) {
            int grow = grow_base + i;
            if (grow >= N_NODES) continue;
            #pragma unroll
            for (int ct = 0; ct < 4; ++ct) {
                float vv = acc[rt][ct][i] + bv[ct];
                vv = vv > 0.f ? vv : 0.f;
                int col = n_base + ct * 16 + l16;
                if (OUT_F16)
                    ((unsigned short*)out)[(size_t)grow * D + col] = f2h(vv);
                else
                    ((float*)out)[(size_t)grow * D + col] = vv;
            }
        }
    }
}

extern "C" void kernel_launch(void* const* d_in, const int* in_sizes, int n_in,
                              void* d_out, int out_size, void* d_ws, size_t ws_size,
                              hipStream_t stream) {
    const float* x  = (const float*)d_in[0];
    const int*   nb = (const int*)d_in[1];
    const float* W1 = (const float*)d_in[2];
    const float* b1 = (const float*)d_in[3];
    const float* W2 = (const float*)d_in[4];
    const float* b2 = (const float*)d_in[5];

    char* ws = (char*)d_ws;
    unsigned short* Wt1 = (unsigned short*)(ws);
    unsigned short* Wt2 = (unsigned short*)(ws + 65536);
    unsigned short* xh  = (unsigned short*)(ws + 131072);              // N x D f16
    unsigned short* h1  = (unsigned short*)(ws + 131072 + 12800000);   // N x D f16

    prep<<<128 + 6250, 256, 0, stream>>>(x, xh, W1, W2, Wt1, Wt2);

    const int mgrid = (N_NODES + BM - 1) / BM;  // 1563
    sage_layer<1><<<mgrid, 128, 0, stream>>>(xh, nb, Wt1, b1, h1);
    sage_layer<0><<<mgrid, 128, 0, stream>>>(h1, nb, Wt2, b2, d_out);
}